// Round 19
// baseline (103.096 us; speedup 1.0000x reference)
//
#include <hip/hip_runtime.h>
#include <stdint.h>

#define IN_F   4096
#define OUT_F  11008
#define BATCH  8
#define WAVES  4
#define RPW    8                  // rows per wave (staged); computed as 2 halves x 4
#define RPB    (WAVES*RPW)        // 32 rows per block
#define NS     4                  // split-K slices
#define SLICE  (IN_F/NS)          // 1024 i per block
#define CHUNK  32                 // i-values per chunk
#define NCHUNK (SLICE/CHUNK)      // 32
#define NSLOT  3                  // ring slots
#define SLOTI  (2*RPB*CHUNK)      // 2048 ints = 8 KB per slot
#define SLOTB  (SLOTI*4)
#define XOFFI  (NSLOT*SLOTI)      // x region starts after ring (ints)
#define XOFFB  (XOFFI*4)          // 24576 bytes

typedef __attribute__((address_space(1))) const uint32_t* gas_t;
typedef __attribute__((address_space(3))) uint32_t* las_t;

// async global->LDS DMA, 16 B/lane: no VGPR destination, regalloc-proof
#define DMA16(gsrc, ldst) \
    __builtin_amdgcn_global_load_lds((gas_t)(gsrc), (las_t)(ldst), 16, 0, 0)

#define SBAR() __builtin_amdgcn_sched_barrier(0)
#define VWAIT(N)                                                             \
    do {                                                                     \
        asm volatile("s_waitcnt vmcnt(" #N ")" ::: "memory");                \
        SBAR();                                                              \
    } while (0)

// compiler-opaque LDS read (no auto vmcnt(0) drain against the DMAs)
#define DSREAD(dst, addr, OFF)                                               \
    asm volatile("ds_read_b32 %0, %1 offset:" #OFF : "=v"(dst) : "v"(addr))

__device__ __forceinline__ float qins_decode(int code, int sgn, float d0, float d1) {
    // |w| = exp2(d0 + code*d1); sign bit straight from the int32 sign (+1 / -1)
    const float e = __builtin_amdgcn_exp2f(fmaf((float)code, d1, d0));
    const uint32_t m = ((uint32_t)sgn) & 0x80000000u;
    return __uint_as_float(__float_as_uint(e) ^ m);
}

// out[b][o] = bias[o]  (out not re-poisoned between replays; re-init each call)
__global__ void qins_init(const float* __restrict__ bias, float* __restrict__ out)
{
    const int o = blockIdx.x * 256 + threadIdx.x;
    const float bv = bias[o];
#pragma unroll
    for (int b = 0; b < BATCH; ++b)
        out[(size_t)b * OUT_F + o] = bv;
}

__global__ __launch_bounds__(256, 2)
void qins_main(const float* __restrict__ x,
               const uint32_t* __restrict__ stored,
               const uint32_t* __restrict__ sign,
               const float* __restrict__ log_min,
               const float* __restrict__ log_max,
               float* __restrict__ out)
{
    // LDS: ring[3][2048 ints] (stored 32x32 @ +0, sign @ +1024 ints)  = 24 KB
    //      x[8][1024 ints] @ XOFFI                                    = 32 KB
    __shared__ int lds[XOFFI + BATCH * SLICE];

    const int tid  = threadIdx.x;
    const int lane = tid & 63;
    const int wave = tid >> 6;
    const int l31  = lane & 31;
    const int sub  = lane >> 5;                  // half-wave: rows sub*4..sub*4+3
    const int rg   = blockIdx.x % (OUT_F / RPB); // row group
    const int s    = blockIdx.x / (OUT_F / RPB); // K-slice
    const int o0   = rg * RPB;
    const int i0   = s * SLICE;

    const float lmin = log_min[0];
    const float lmax = log_max[0];
    const float L2E  = 1.44269504088896340736f;
    // log2(|w|) = d0 + code*d1
    const float d1 = -(lmax - lmin) * (L2E / 254.0f);
    const float d0 = (lmin + (lmax - lmin) * (255.0f / 254.0f)) * L2E;

    // ---- x slice staged ONCE: 8 batches x 1024 ints, one int4 per thread/batch
#pragma unroll
    for (int b = 0; b < BATCH; ++b) {
        reinterpret_cast<int4*>(&lds[XOFFI + b * SLICE])[tid] =
            reinterpret_cast<const int4*>((const int*)x + b * IN_F + i0)[tid];
    }
    __syncthreads();   // x visible to all waves (drains x loads; ring not yet issued)

    // ---- weight DMA sources: wave stages its 8 rows; lane -> row wave*8+(lane>>3),
    //      16 B at int-offset (lane&7)*4 within the 32-int chunk row
    const uint32_t* gs = stored + (size_t)(o0 + wave * 8 + (lane >> 3)) * IN_F
                       + i0 + (lane & 7) * 4;
    const uint32_t* gg = sign   + (size_t)(o0 + wave * 8 + (lane >> 3)) * IN_F
                       + i0 + (lane & 7) * 4;

#define ISSUE(T, K)                                                          \
    do {                                                                     \
        DMA16(gs + (K) * CHUNK, &lds[(T) * SLOTI + wave * 256]);             \
        DMA16(gg + (K) * CHUNK, &lds[(T) * SLOTI + 1024 + wave * 256]);      \
    } while (0)

    float acc[4][BATCH];
#pragma unroll
    for (int r = 0; r < 4; ++r)
#pragma unroll
        for (int b = 0; b < BATCH; ++b) acc[r][b] = 0.0f;

    const uint32_t ldsb = (uint32_t)(uintptr_t)(las_t)&lds[0];
    // weight read base: slot 0, this wave's segment, this half's rows, this lane's i
    const uint32_t wbase = ldsb + (uint32_t)(wave * 256 + sub * 128 + l31) * 4u;
    // x read base: x region, this lane's i (chunk k adds k*128 bytes)
    const uint32_t xbase = ldsb + XOFFB + (uint32_t)l31 * 4u;

    // prologue: chunks 0,1 in flight (4 outstanding DMAs per wave)
    ISSUE(0, 0);
    ISSUE(1, 1);
    SBAR();

    int cur = 0, iss = 2;
#pragma unroll 1
    for (int k = 0; k < NCHUNK; ++k) {
        if (k < NCHUNK - 1) VWAIT(2);   // chunk k landed; k+1 stays in flight
        else                VWAIT(0);
        __builtin_amdgcn_s_barrier();   // raw barrier: no vmcnt(0) drain
        SBAR();

        if (k + 2 < NCHUNK)
            ISSUE(iss, k + 2);          // refill reclaimed slot
        SBAR();

        // compute chunk k: 4 rows (this half) x 8 batches, one i per lane
        {
            const uint32_t aw = wbase + (uint32_t)cur * SLOTB;
            const uint32_t ax = xbase + (uint32_t)k * (CHUNK * 4);
            int c0, c1, c2, c3, g0, g1, g2, g3, xw[BATCH];
            DSREAD(c0, aw, 0);       // stored rows sub*4 + 0..3 (32 ints apart)
            DSREAD(c1, aw, 128);
            DSREAD(c2, aw, 256);
            DSREAD(c3, aw, 384);
            DSREAD(g0, aw, 4096);    // sign region (+1024 ints)
            DSREAD(g1, aw, 4224);
            DSREAD(g2, aw, 4352);
            DSREAD(g3, aw, 4480);
            DSREAD(xw[0], ax, 0);        // x batch b at +b*4096 bytes
            DSREAD(xw[1], ax, 4096);
            DSREAD(xw[2], ax, 8192);
            DSREAD(xw[3], ax, 12288);
            DSREAD(xw[4], ax, 16384);
            DSREAD(xw[5], ax, 20480);
            DSREAD(xw[6], ax, 24576);
            DSREAD(xw[7], ax, 28672);
            asm volatile("s_waitcnt lgkmcnt(0)" ::: "memory");
            SBAR();                  // rule #18

            const float w0 = qins_decode(c0, g0, d0, d1);
            const float w1 = qins_decode(c1, g1, d0, d1);
            const float w2 = qins_decode(c2, g2, d0, d1);
            const float w3 = qins_decode(c3, g3, d0, d1);
#pragma unroll
            for (int b = 0; b < BATCH; ++b) {
                const float xv = __int_as_float(xw[b]);
                acc[0][b] = fmaf(w0, xv, acc[0][b]);
                acc[1][b] = fmaf(w1, xv, acc[1][b]);
                acc[2][b] = fmaf(w2, xv, acc[2][b]);
                acc[3][b] = fmaf(w3, xv, acc[3][b]);
            }
        }

        cur = (cur == NSLOT - 1) ? 0 : cur + 1;
        iss = (iss == NSLOT - 1) ? 0 : iss + 1;
    }

    // reduce over the 32 lanes of each half-wave (sums this slice's i)
#pragma unroll
    for (int r = 0; r < 4; ++r)
#pragma unroll
        for (int b = 0; b < BATCH; ++b) {
            float v = acc[r][b];
#pragma unroll
            for (int sft = 16; sft >= 1; sft >>= 1)
                v += __shfl_xor(v, sft, 64);
            acc[r][b] = v;
        }

    if (l31 == 0) {
#pragma unroll
        for (int r = 0; r < 4; ++r) {
            const int row = o0 + wave * 8 + sub * 4 + r;
#pragma unroll
            for (int b = 0; b < BATCH; ++b)
                atomicAdd(out + (size_t)b * OUT_F + row, acc[r][b]);
        }
    }
#undef ISSUE
}

extern "C" void kernel_launch(void* const* d_in, const int* in_sizes, int n_in,
                              void* d_out, int out_size, void* d_ws, size_t ws_size,
                              hipStream_t stream)
{
    const float*    x      = (const float*)d_in[0];
    const uint32_t* stored = (const uint32_t*)d_in[1];
    const uint32_t* sign   = (const uint32_t*)d_in[2];
    const float*    lmin   = (const float*)d_in[3];
    const float*    lmax   = (const float*)d_in[4];
    const float*    bias   = (const float*)d_in[5];
    float* out = (float*)d_out;

    qins_init<<<dim3(OUT_F / 256), dim3(256), 0, stream>>>(bias, out);
    qins_main<<<dim3((OUT_F / RPB) * NS), dim3(256), 0, stream>>>(
        x, stored, sign, lmin, lmax, out);
}

// Round 21
// 71.852 us; speedup vs baseline: 1.4348x; 1.4348x over previous
//
#include <hip/hip_runtime.h>
#include <stdint.h>

#define IN_F   4096
#define OUT_F  11008
#define BATCH  8
#define WAVES  4
#define RPW    2                  // rows per wave
#define RPB    (WAVES*RPW)        // 8 rows per block
#define CHUNK  128                // i-values per chunk
#define NCHUNK (IN_F/CHUNK)       // 32
#define SLOTI  (3*RPB*CHUNK)      // 3072 ints = 12 KB per slot (stored|sign|x)
#define SLOTB  (SLOTI*4)

typedef __attribute__((address_space(3))) uint32_t* las_t;
typedef int i32x2 __attribute__((ext_vector_type(2)));
typedef int i32x4 __attribute__((ext_vector_type(4)));   // register tuple, asm-legal

#define SBAR() __builtin_amdgcn_sched_barrier(0)
#define LGKM0() asm volatile("s_waitcnt lgkmcnt(0)" ::: "memory")

// compiler-opaque LDS ops (R18-proven): no auto vmcnt(0) drain, no reordering
#define DSREAD(dst, addr, OFF)                                               \
    asm volatile("ds_read_b64 %0, %1 offset:" #OFF : "=v"(dst) : "v"(addr))
#define DSWRITE(addr, data, OFF)                                             \
    asm volatile("ds_write_b128 %0, %1 offset:" #OFF                         \
                 :: "v"(addr), "v"(data) : "memory")

__device__ __forceinline__ float qins_decode(int code, int sgn, float d0, float d1) {
    // |w| = exp2(d0 + code*d1); sign bit straight from the int32 sign (+1 / -1)
    const float e = __builtin_amdgcn_exp2f(fmaf((float)code, d1, d0));
    const uint32_t m = ((uint32_t)sgn) & 0x80000000u;
    return __uint_as_float(__float_as_uint(e) ^ m);
}

__global__ __launch_bounds__(256, 2)
void qins_linear_kernel(const float* __restrict__ x,
                        const int* __restrict__ stored,
                        const int* __restrict__ sign,
                        const float* __restrict__ log_min,
                        const float* __restrict__ log_max,
                        const float* __restrict__ bias,
                        float* __restrict__ out)
{
    // slot (ints): [0,1024) stored 8x128 | [1024,2048) sign | [2048,3072) x
    __shared__ int lds[2][SLOTI];

    const int tid  = threadIdx.x;
    const int lane = tid & 63;
    const int wave = tid >> 6;
    const int o0   = blockIdx.x * RPB;

    const float lmin = log_min[0];
    const float lmax = log_max[0];
    const float L2E  = 1.44269504088896340736f;
    const float d1 = -(lmax - lmin) * (L2E / 254.0f);
    const float d0 = (lmin + (lmax - lmin) * (255.0f / 254.0f)) * L2E;

    // global sources: lanes 0-31 -> row/batch 2w, lanes 32-63 -> 2w+1
    const int sub = lane >> 5;
    const int i32 = (lane & 31) * 4;
    const int* gs = stored + (size_t)(o0 + 2 * wave + sub) * IN_F + i32;
    const int* gg = sign   + (size_t)(o0 + 2 * wave + sub) * IN_F + i32;
    const int* gx = (const int*)x + (size_t)(2 * wave + sub) * IN_F + i32;

    // reg-staging sets: loads pinned early by SBAR fences (R9 proved they hold)
    i32x4 As, Ag, Ax, Bs, Bg, Bx;
#define GLOAD(P, K)                                                          \
    do {                                                                     \
        const int _ip = (K) * CHUNK;                                         \
        P##s = *reinterpret_cast<const i32x4*>(gs + _ip);                    \
        P##g = *reinterpret_cast<const i32x4*>(gg + _ip);                    \
        P##x = *reinterpret_cast<const i32x4*>(gx + _ip);                    \
    } while (0)

    // LDS write base: this wave's 1KB segment of each region
    const uint32_t ldsb = (uint32_t)(uintptr_t)(las_t)&lds[0][0];
    const uint32_t wrb  = ldsb + (uint32_t)(wave * 1024 + lane * 16);
#define WRITE(P, SLOT)                                                       \
    do {                                                                     \
        const uint32_t _a = wrb + (SLOT) * SLOTB;                            \
        DSWRITE(_a, P##s, 0);                                                \
        DSWRITE(_a, P##g, 4096);                                             \
        DSWRITE(_a, P##x, 8192);                                             \
    } while (0)

    // LDS read bases (R18-proven layout)
    const uint32_t baseW = ldsb + (uint32_t)(wave * 1024 + lane * 8);
    const uint32_t baseX = ldsb + 8192u + (uint32_t)(lane * 8);

    float acc[RPW][BATCH];
#pragma unroll
    for (int r = 0; r < RPW; ++r)
#pragma unroll
        for (int b = 0; b < BATCH; ++b) acc[r][b] = 0.0f;

#define COMPUTE(K, SLOT)                                                     \
    do {                                                                     \
        const uint32_t aw = baseW + (SLOT) * SLOTB;                          \
        const uint32_t ax = baseX + (SLOT) * SLOTB;                          \
        i32x2 c0, c1, g0, g1, xv[BATCH];                                     \
        DSREAD(c0, aw, 0);                                                   \
        DSREAD(c1, aw, 512);                                                 \
        DSREAD(g0, aw, 4096);                                                \
        DSREAD(g1, aw, 4608);                                                \
        DSREAD(xv[0], ax, 0);                                                \
        DSREAD(xv[1], ax, 512);                                              \
        DSREAD(xv[2], ax, 1024);                                             \
        DSREAD(xv[3], ax, 1536);                                             \
        DSREAD(xv[4], ax, 2048);                                             \
        DSREAD(xv[5], ax, 2560);                                             \
        DSREAD(xv[6], ax, 3072);                                             \
        DSREAD(xv[7], ax, 3584);                                             \
        LGKM0();                                                             \
        SBAR();                                                              \
        const float w00 = qins_decode(c0.x, g0.x, d0, d1);                   \
        const float w01 = qins_decode(c0.y, g0.y, d0, d1);                   \
        const float w10 = qins_decode(c1.x, g1.x, d0, d1);                   \
        const float w11 = qins_decode(c1.y, g1.y, d0, d1);                   \
        _Pragma("unroll")                                                    \
        for (int b = 0; b < BATCH; ++b) {                                    \
            const float xlo = __int_as_float(xv[b].x);                       \
            const float xhi = __int_as_float(xv[b].y);                       \
            acc[0][b] = fmaf(w01, xhi, fmaf(w00, xlo, acc[0][b]));           \
            acc[1][b] = fmaf(w11, xhi, fmaf(w10, xlo, acc[1][b]));           \
        }                                                                    \
    } while (0)

#define BARRIER()                                                            \
    do {                                                                     \
        LGKM0();                                                             \
        SBAR();                                                              \
        __builtin_amdgcn_s_barrier();                                        \
        SBAR();                                                              \
    } while (0)

    // prologue: chunk 0 -> slot0 (full wait, once), chunk 1 in flight in A
    GLOAD(B, 0);
    WRITE(B, 0);                 // compiler inserts vmcnt wait for B's loads
    GLOAD(A, 1);
    BARRIER();

    // steady state, unrolled x2: chunk m lives in slot[m&1]
#pragma unroll 1
    for (int k = 0; k < NCHUNK - 2; k += 2) {
        // iter k: A holds chunk k+1; prefetch B <- k+2
        GLOAD(B, k + 2);
        SBAR();
        COMPUTE(k, 0);
        SBAR();
        WRITE(A, 1);             // counted vmcnt: waits A only, B stays in flight
        BARRIER();
        // iter k+1: B holds chunk k+2; prefetch A <- k+3
        if (k + 3 < NCHUNK) { GLOAD(A, k + 3); }
        SBAR();
        COMPUTE(k + 1, 1);
        SBAR();
        WRITE(B, 0);
        BARRIER();
    }
    // tail: chunks NCHUNK-2 (slot0) and NCHUNK-1 (in A -> slot1)
    COMPUTE(NCHUNK - 2, 0);
    SBAR();
    WRITE(A, 1);
    BARRIER();
    COMPUTE(NCHUNK - 1, 1);

    // butterfly reduction of the 16 (row,batch) partials across the wave
#pragma unroll
    for (int r = 0; r < RPW; ++r)
#pragma unroll
        for (int b = 0; b < BATCH; ++b) {
            float v = acc[r][b];
#pragma unroll
            for (int s = 32; s >= 1; s >>= 1)
                v += __shfl_xor(v, s, 64);
            acc[r][b] = v;
        }

    if (lane == 0) {
#pragma unroll
        for (int r = 0; r < RPW; ++r) {
            const int row = o0 + 2 * wave + r;
            const float bv = bias[row];
#pragma unroll
            for (int b = 0; b < BATCH; ++b)
                out[(size_t)b * OUT_F + row] = acc[r][b] + bv;
        }
    }
}

extern "C" void kernel_launch(void* const* d_in, const int* in_sizes, int n_in,
                              void* d_out, int out_size, void* d_ws, size_t ws_size,
                              hipStream_t stream)
{
    const float* x      = (const float*)d_in[0];
    const int*   stored = (const int*)d_in[1];
    const int*   sign   = (const int*)d_in[2];
    const float* lmin   = (const float*)d_in[3];
    const float* lmax   = (const float*)d_in[4];
    const float* bias   = (const float*)d_in[5];
    float* out = (float*)d_out;

    dim3 grid(OUT_F / RPB), block(WAVES * 64);
    qins_linear_kernel<<<grid, block, 0, stream>>>(x, stored, sign, lmin, lmax, bias, out);
}